// Round 1
// baseline (2819.184 us; speedup 1.0000x reference)
//
#include <hip/hip_runtime.h>
#include <hip/hip_bf16.h>
#include <math.h>

// Problem constants (pinned by reference)
constexpr int BB = 4;
constexpr int TT = 512;
constexpr int DD = 2048;
constexpr int HH = 6;
constexpr int KK = 256;   // head_k_dim
constexpr int VV = 512;   // head_v_dim
constexpr int NHOUSE = 2;
constexpr int MM = BB * TT;          // 2048 rows
constexpr int KEY_DIM = HH * KK;     // 1536
constexpr int VAL_DIM = HH * VV;     // 3072

__device__ __forceinline__ float rsqrt_nr(float x) {
  float r = rsqrtf(x);
  return r * (1.5f - 0.5f * x * r * r);   // one NR step -> ~fp32 accurate
}
__device__ __forceinline__ float sigmoidf_(float x) {
  return 1.f / (1.f + expf(-x));
}

// ---------------------------------------------------------------------------
// C = act(A * W^T): A [M,Kd] row-major, W [N,Kd] row-major, C [M,N] row-major.
// Requires M%64==0, N%64==0, Kd%16==0. act: 0=none, 1=silu.
// 64x64 block tile, 256 threads, 4x4 per thread.
// ---------------------------------------------------------------------------
__global__ __launch_bounds__(256) void gemm_awt(const float* __restrict__ A,
                                                const float* __restrict__ W,
                                                float* __restrict__ C,
                                                int M, int N, int Kd, int act) {
  __shared__ __align__(16) float As[16][68];  // [k][m], +4 pad keeps 16B align, ~2-way banks
  __shared__ __align__(16) float Ws[16][68];  // [k][n]
  const int tid = threadIdx.x;
  const int tn = tid & 15;        // 0..15 -> n subtile
  const int tm = tid >> 4;        // 0..15 -> m subtile
  const int lrow = tid >> 2;      // 0..63 load row
  const int lk4 = (tid & 3) << 2; // 0,4,8,12 load k-offset

  const float* Ab = A + (size_t)(blockIdx.x * 64 + lrow) * Kd + lk4;
  const float* Wb = W + (size_t)(blockIdx.y * 64 + lrow) * Kd + lk4;

  float acc[4][4] = {};

  for (int k0 = 0; k0 < Kd; k0 += 16) {
    float4 av = *(const float4*)(Ab + k0);
    float4 wv = *(const float4*)(Wb + k0);
    __syncthreads();
    As[lk4 + 0][lrow] = av.x; As[lk4 + 1][lrow] = av.y;
    As[lk4 + 2][lrow] = av.z; As[lk4 + 3][lrow] = av.w;
    Ws[lk4 + 0][lrow] = wv.x; Ws[lk4 + 1][lrow] = wv.y;
    Ws[lk4 + 2][lrow] = wv.z; Ws[lk4 + 3][lrow] = wv.w;
    __syncthreads();
#pragma unroll
    for (int kk = 0; kk < 16; ++kk) {
      float4 a = *(const float4*)&As[kk][tm * 4];
      float4 b = *(const float4*)&Ws[kk][tn * 4];
      acc[0][0] = fmaf(a.x, b.x, acc[0][0]); acc[0][1] = fmaf(a.x, b.y, acc[0][1]);
      acc[0][2] = fmaf(a.x, b.z, acc[0][2]); acc[0][3] = fmaf(a.x, b.w, acc[0][3]);
      acc[1][0] = fmaf(a.y, b.x, acc[1][0]); acc[1][1] = fmaf(a.y, b.y, acc[1][1]);
      acc[1][2] = fmaf(a.y, b.z, acc[1][2]); acc[1][3] = fmaf(a.y, b.w, acc[1][3]);
      acc[2][0] = fmaf(a.z, b.x, acc[2][0]); acc[2][1] = fmaf(a.z, b.y, acc[2][1]);
      acc[2][2] = fmaf(a.z, b.z, acc[2][2]); acc[2][3] = fmaf(a.z, b.w, acc[2][3]);
      acc[3][0] = fmaf(a.w, b.x, acc[3][0]); acc[3][1] = fmaf(a.w, b.y, acc[3][1]);
      acc[3][2] = fmaf(a.w, b.z, acc[3][2]); acc[3][3] = fmaf(a.w, b.w, acc[3][3]);
    }
  }

#pragma unroll
  for (int i = 0; i < 4; ++i) {
    float4 r;
    r.x = acc[i][0]; r.y = acc[i][1]; r.z = acc[i][2]; r.w = acc[i][3];
    if (act == 1) {
      r.x = r.x * sigmoidf_(r.x); r.y = r.y * sigmoidf_(r.y);
      r.z = r.z * sigmoidf_(r.z); r.w = r.w * sigmoidf_(r.w);
    }
    float* cp = C + (size_t)(blockIdx.x * 64 + tm * 4 + i) * N + blockIdx.y * 64 + tn * 4;
    *(float4*)cp = r;
  }
}

// ---------------------------------------------------------------------------
// Small projections: y = x @ [Wb;Wa]^T per row (18 outputs), then
// beta = 2*sigmoid(yb), gexp = exp(-exp(A_log)*softplus(ya + dt_bias)).
// grid = MM blocks of 256 threads.
// ---------------------------------------------------------------------------
__global__ __launch_bounds__(256) void small_proj(const float* __restrict__ x,
                                                  const float* __restrict__ Wb,
                                                  const float* __restrict__ Wa,
                                                  const float* __restrict__ A_log,
                                                  const float* __restrict__ dt_bias,
                                                  float* __restrict__ beta_out,
                                                  float* __restrict__ gexp_out) {
  const int m = blockIdx.x;
  const int tid = threadIdx.x;
  const int lane = tid & 63;
  const int wv = tid >> 6;
  __shared__ float xs[DD];
  __shared__ float ybuf[18];
#pragma unroll
  for (int i = 0; i < DD / 256; ++i) xs[tid + 256 * i] = x[(size_t)m * DD + tid + 256 * i];
  __syncthreads();
  for (int n = wv; n < 18; n += 4) {
    const float* wrow = (n < 12) ? (Wb + (size_t)n * DD) : (Wa + (size_t)(n - 12) * DD);
    float p = 0.f;
#pragma unroll
    for (int i = 0; i < DD / 64; ++i) p = fmaf(xs[lane + 64 * i], wrow[lane + 64 * i], p);
#pragma unroll
    for (int off = 32; off; off >>= 1) p += __shfl_xor(p, off);
    if (lane == 0) ybuf[n] = p;
  }
  __syncthreads();
  if (tid < 12) {
    beta_out[(size_t)m * 12 + tid] = 2.f * sigmoidf_(ybuf[tid]);
  } else if (tid < 18) {
    int hh = tid - 12;
    float z = ybuf[tid] + dt_bias[hh];
    float sp = fmaxf(z, 0.f) + log1pf(expf(-fabsf(z)));  // stable softplus
    float g = -expf(A_log[hh]) * sp;
    gexp_out[(size_t)m * HH + hh] = expf(g);
  }
}

// ---------------------------------------------------------------------------
// Sequential delta-rule recurrence. Grid = BB*HH*(VV/16) = 768 blocks, 256 thr.
// Block owns chain (b,h) and 16 v-columns; state h[256][16] in registers
// (thread (vl,kq) holds h[kq*16 + 0..15][vl]). k/q staged in double-buffered
// LDS with +4/16 padding (16B-aligned float4 fragments, 2-way banks = free).
// One barrier per timestep; next step's globals prefetched before compute.
// ---------------------------------------------------------------------------
__global__ __launch_bounds__(256) void recurrence(const float* __restrict__ qa,
                                                  const float* __restrict__ ka,
                                                  const float* __restrict__ va,
                                                  const float* __restrict__ beta,
                                                  const float* __restrict__ gexp,
                                                  float* __restrict__ o) {
  constexpr int CH = VV / 16;  // 32 v-chunks
  const int bid = blockIdx.x;
  const int b = bid / (HH * CH);
  const int rem = bid % (HH * CH);
  const int hh = rem / CH;
  const int v0 = (rem % CH) * 16;
  const int tid = threadIdx.x;
  const int vl = tid >> 4;   // v column 0..15
  const int kq = tid & 15;   // k quarter 0..15
  const int lane = tid & 63;
  const int wv = tid >> 6;
  const int pidx = tid + 4 * (tid >> 4);  // padded LDS index for staging

  __shared__ __align__(16) float ks[2][2][320];  // [buf][j][k + 4*(k/16)]
  __shared__ __align__(16) float qs[2][320];
  __shared__ float vs[2][2][16];
  __shared__ float bs[2][2];
  __shared__ float gs[2];
  __shared__ float nr[2][2][4];

  float hreg[16];
#pragma unroll
  for (int i = 0; i < 16; ++i) hreg[i] = 0.f;

  const float scale = 0.0625f;  // 256^-0.5

  // prologue: stage t=0 into buf 0
  {
    const int m = b * TT;
    float rq = qa[(size_t)(m * HH + hh) * KK + tid] * scale;
    float rk0 = ka[(size_t)((m * NHOUSE + 0) * HH + hh) * KK + tid];
    float rk1 = ka[(size_t)((m * NHOUSE + 1) * HH + hh) * KK + tid];
    float s0 = rk0 * rk0, s1 = rk1 * rk1;
#pragma unroll
    for (int off = 32; off; off >>= 1) { s0 += __shfl_xor(s0, off); s1 += __shfl_xor(s1, off); }
    if (lane == 0) { nr[0][0][wv] = s0; nr[0][1][wv] = s1; }
    ks[0][0][pidx] = rk0; ks[0][1][pidx] = rk1; qs[0][pidx] = rq;
    if (tid < 32) vs[0][tid >> 4][tid & 15] =
        va[(size_t)((m * NHOUSE + (tid >> 4)) * HH + hh) * VV + v0 + (tid & 15)];
    if (tid >= 32 && tid < 34) bs[0][tid - 32] = beta[(size_t)(m * NHOUSE + (tid - 32)) * HH + hh];
    if (tid == 34) gs[0] = gexp[(size_t)m * HH + hh];
  }
  __syncthreads();

  for (int t = 0; t < TT; ++t) {
    const int buf = t & 1;
    const int nb = buf ^ 1;
    const int tnx = (t + 1 < TT) ? (t + 1) : t;
    const int mn = b * TT + tnx;

    // ---- prefetch next step's globals into registers ----
    float rq = qa[(size_t)(mn * HH + hh) * KK + tid] * scale;
    float rk0 = ka[(size_t)((mn * NHOUSE + 0) * HH + hh) * KK + tid];
    float rk1 = ka[(size_t)((mn * NHOUSE + 1) * HH + hh) * KK + tid];
    float rv = 0.f, rb = 0.f, rg = 0.f;
    if (tid < 32) rv = va[(size_t)((mn * NHOUSE + (tid >> 4)) * HH + hh) * VV + v0 + (tid & 15)];
    if (tid >= 32 && tid < 34) rb = beta[(size_t)(mn * NHOUSE + (tid - 32)) * HH + hh];
    if (tid == 34) rg = gexp[(size_t)mn * HH + hh];

    // ---- compute step t from buf ----
    float n0 = nr[buf][0][0] + nr[buf][0][1] + nr[buf][0][2] + nr[buf][0][3];
    float n1 = nr[buf][1][0] + nr[buf][1][1] + nr[buf][1][2] + nr[buf][1][3];
    float invj[2];
    invj[0] = rsqrt_nr(fmaxf(n0, 1e-24f));  // == 1/max(sqrt(n),1e-12)
    invj[1] = rsqrt_nr(fmaxf(n1, 1e-24f));
    const float ge = gs[buf];
    float bj[2];
    bj[0] = bs[buf][0] * invj[0];
    bj[1] = bs[buf][1] * invj[1];

#pragma unroll
    for (int i = 0; i < 16; ++i) hreg[i] *= ge;

#pragma unroll
    for (int j = 0; j < 2; ++j) {
      const float4* kb = (const float4*)&ks[buf][j][kq * 20];
      float4 x0 = kb[0], x1 = kb[1], x2 = kb[2], x3 = kb[3];
      float rk[16] = {x0.x, x0.y, x0.z, x0.w, x1.x, x1.y, x1.z, x1.w,
                      x2.x, x2.y, x2.z, x2.w, x3.x, x3.y, x3.z, x3.w};
      float p = 0.f;
#pragma unroll
      for (int i = 0; i < 16; ++i) p = fmaf(hreg[i], rk[i], p);
      p += __shfl_xor(p, 1); p += __shfl_xor(p, 2);
      p += __shfl_xor(p, 4); p += __shfl_xor(p, 8);
      p *= invj[j];
      const float wgt = bj[j] * (vs[buf][j][vl] - p);
#pragma unroll
      for (int i = 0; i < 16; ++i) hreg[i] = fmaf(wgt, rk[i], hreg[i]);
    }

    {
      const float4* qb = (const float4*)&qs[buf][kq * 20];
      float4 x0 = qb[0], x1 = qb[1], x2 = qb[2], x3 = qb[3];
      float qv[16] = {x0.x, x0.y, x0.z, x0.w, x1.x, x1.y, x1.z, x1.w,
                      x2.x, x2.y, x2.z, x2.w, x3.x, x3.y, x3.z, x3.w};
      float p = 0.f;
#pragma unroll
      for (int i = 0; i < 16; ++i) p = fmaf(hreg[i], qv[i], p);
      p += __shfl_xor(p, 1); p += __shfl_xor(p, 2);
      p += __shfl_xor(p, 4); p += __shfl_xor(p, 8);
      if (kq == 0) o[(size_t)((b * TT + t) * HH + hh) * VV + v0 + vl] = p;
    }

    // ---- stage t+1 into the other buffer ----
    float s0 = rk0 * rk0, s1 = rk1 * rk1;
#pragma unroll
    for (int off = 32; off; off >>= 1) { s0 += __shfl_xor(s0, off); s1 += __shfl_xor(s1, off); }
    if (lane == 0) { nr[nb][0][wv] = s0; nr[nb][1][wv] = s1; }
    ks[nb][0][pidx] = rk0; ks[nb][1][pidx] = rk1; qs[nb][pidx] = rq;
    if (tid < 32) vs[nb][tid >> 4][tid & 15] = rv;
    if (tid >= 32 && tid < 34) bs[nb][tid - 32] = rb;
    if (tid == 34) gs[nb] = rg;
    __syncthreads();
  }
}

// ---------------------------------------------------------------------------
// Gated RMSNorm (in-place capable). grid = MM*HH rows of 512, 256 threads.
// ---------------------------------------------------------------------------
__global__ __launch_bounds__(256) void rms_gate_kernel(const float* __restrict__ o,
                                                       const float* __restrict__ gate,
                                                       const float* __restrict__ w,
                                                       float* __restrict__ out) {
  const int row = blockIdx.x;
  const int tid = threadIdx.x;
  const float* op = o + (size_t)row * VV;
  const float* gp = gate + (size_t)row * VV;
  float a0 = op[tid], a1 = op[tid + 256];
  float ss = a0 * a0 + a1 * a1;
#pragma unroll
  for (int off = 32; off; off >>= 1) ss += __shfl_xor(ss, off);
  __shared__ float red[4];
  const int lane = tid & 63, wv = tid >> 6;
  if (lane == 0) red[wv] = ss;
  __syncthreads();
  float tot = red[0] + red[1] + red[2] + red[3];
  float inv = rsqrt_nr(tot * (1.f / (float)VV) + 1e-5f);
  float g0 = gp[tid], g1 = gp[tid + 256];
  float r0 = a0 * inv * w[tid] * sigmoidf_(g0);
  float r1 = a1 * inv * w[tid + 256] * sigmoidf_(g1);
  float* outp = out + (size_t)row * VV;
  outp[tid] = r0;
  outp[tid + 256] = r1;
}

// ---------------------------------------------------------------------------
extern "C" void kernel_launch(void* const* d_in, const int* in_sizes, int n_in,
                              void* d_out, int out_size, void* d_ws, size_t ws_size,
                              hipStream_t stream) {
  (void)in_sizes; (void)n_in; (void)out_size; (void)ws_size;
  const float* x       = (const float*)d_in[0];
  const float* Wq      = (const float*)d_in[1];
  const float* Wk      = (const float*)d_in[2];
  const float* Wv      = (const float*)d_in[3];
  const float* Wb      = (const float*)d_in[4];
  const float* Wa      = (const float*)d_in[5];
  const float* A_log   = (const float*)d_in[6];
  const float* dt_bias = (const float*)d_in[7];
  const float* Wg      = (const float*)d_in[8];
  const float* Wo      = (const float*)d_in[9];
  const float* onw     = (const float*)d_in[10];
  float* out = (float*)d_out;
  float* ws = (float*)d_ws;

  // workspace layout (floats)
  size_t off = 0;
  float* q_act  = ws + off; off += (size_t)MM * KEY_DIM;            // 3.15M
  float* k_act  = ws + off; off += (size_t)MM * KEY_DIM * NHOUSE;   // 6.29M
  float* v_act  = ws + off; off += (size_t)MM * VAL_DIM * NHOUSE;   // 12.58M
  float* beta_w = ws + off; off += (size_t)MM * NHOUSE * HH;        // 24K
  float* gexp_w = ws + off; off += (size_t)MM * HH;                 // 12K
  float* gate_w = ws + off; off += (size_t)MM * VAL_DIM;            // 6.29M
  float* o_mid  = ws + off; off += (size_t)MM * VAL_DIM;            // 6.29M

  // 1. projections (fused silu) + gate
  gemm_awt<<<dim3(MM / 64, KEY_DIM / 64), 256, 0, stream>>>(x, Wq, q_act, MM, KEY_DIM, DD, 1);
  gemm_awt<<<dim3(MM / 64, (KEY_DIM * NHOUSE) / 64), 256, 0, stream>>>(x, Wk, k_act, MM, KEY_DIM * NHOUSE, DD, 1);
  gemm_awt<<<dim3(MM / 64, (VAL_DIM * NHOUSE) / 64), 256, 0, stream>>>(x, Wv, v_act, MM, VAL_DIM * NHOUSE, DD, 1);
  gemm_awt<<<dim3(MM / 64, VAL_DIM / 64), 256, 0, stream>>>(x, Wg, gate_w, MM, VAL_DIM, DD, 0);
  small_proj<<<MM, 256, 0, stream>>>(x, Wb, Wa, A_log, dt_bias, beta_w, gexp_w);

  // 2. sequential delta-rule recurrence
  recurrence<<<BB * HH * (VV / 16), 256, 0, stream>>>(q_act, k_act, v_act, beta_w, gexp_w, o_mid);

  // 3. gated RMSNorm (in place) + output projection
  rms_gate_kernel<<<MM * HH, 256, 0, stream>>>(o_mid, gate_w, onw, o_mid);
  gemm_awt<<<dim3(MM / 64, DD / 64), 256, 0, stream>>>(o_mid, Wo, out, MM, DD, VAL_DIM, 0);
}

// Round 4
// 1333.560 us; speedup vs baseline: 2.1140x; 2.1140x over previous
//
#include <hip/hip_runtime.h>
#include <hip/hip_bf16.h>
#include <math.h>

// Problem constants (pinned by reference)
constexpr int BB = 4;
constexpr int TT = 512;
constexpr int DD = 2048;
constexpr int HH = 6;
constexpr int KK = 256;   // head_k_dim
constexpr int VV = 512;   // head_v_dim
constexpr int NHOUSE = 2;
constexpr int MM = BB * TT;          // 2048 rows
constexpr int KEY_DIM = HH * KK;     // 1536
constexpr int VAL_DIM = HH * VV;     // 3072

// qkv fp32 buffer: row stride 10752, col ranges q[0,1536) k[1536,4608) v[4608,10752)
constexpr int QKV_ST = 10752;
constexpr int QOFF = 0;
constexpr int KOFF = 1536;
constexpr int VOFF = 4608;

// ---- workspace layout (FLOAT units), constexpr to avoid literal mistakes ----
// f16 regions: element_count / 2 floats.
constexpr size_t SZ_QKV  = (size_t)MM * QKV_ST;          // 22,020,096
constexpr size_t SZ_GATE = (size_t)MM * VAL_DIM / 2;     //  3,145,728 (f16)
constexpr size_t SZ_BETA = (size_t)MM * NHOUSE * HH;     //     24,576
constexpr size_t SZ_GEXP = (size_t)MM * HH;              //     12,288
constexpr size_t SZ_X16  = (size_t)MM * DD / 2;          //  2,097,152 (f16)
constexpr size_t SZ_W16  = (size_t)3072 * DD / 2;        //  3,145,728 (f16, max chunk)
constexpr size_t SZ_OMID = (size_t)MM * VAL_DIM;         //  6,291,456

constexpr size_t OFF_QKV  = 0;
constexpr size_t OFF_GATE = OFF_QKV + SZ_QKV;
constexpr size_t OFF_BETA = OFF_GATE + SZ_GATE;
constexpr size_t OFF_GEXP = OFF_BETA + SZ_BETA;
constexpr size_t OFF_X16  = OFF_GEXP + SZ_GEXP;
constexpr size_t OFF_W16  = OFF_X16 + SZ_X16;
// o_mid overlays x16+wf16 (both dead after the last projection GEMM);
// it extends ~1 MB past wf16's end.
constexpr size_t OFF_OMID = OFF_X16;
constexpr size_t WS_PEAK  = OFF_OMID + SZ_OMID;          // 31,494,144 fl = 126.0 MB
static_assert(OFF_OMID + SZ_OMID >= OFF_W16 + SZ_W16, "omid covers w16");
static_assert(WS_PEAK <= 34600000, "stay under round-1-proven 138.5 MB");
// post-recurrence reuse of dead qkv region:
constexpr size_t OFF_O2   = 0;                           // MM*VAL_DIM f16 = 3,145,728 fl
constexpr size_t OFF_WO16 = SZ_GATE;                     // DD*VAL_DIM f16 = 3,145,728 fl
static_assert(OFF_WO16 + (size_t)DD * VAL_DIM / 2 <= SZ_QKV, "o2+wo16 fit in dead qkv");

__device__ __forceinline__ float rsqrt_nr(float x) {
  float r = rsqrtf(x);
  return r * (1.5f - 0.5f * x * r * r);
}
__device__ __forceinline__ float sigmoidf_(float x) {
  return 1.f / (1.f + expf(-x));
}
__device__ __forceinline__ short f2h(float f) {
  _Float16 h = (_Float16)f;
  short s;
  __builtin_memcpy(&s, &h, 2);
  return s;
}

typedef __attribute__((ext_vector_type(8))) _Float16 f16x8;
typedef __attribute__((ext_vector_type(4))) float f32x4;

__device__ __forceinline__ void gload_lds16(const short* g, short* l) {
  __builtin_amdgcn_global_load_lds(
      (const __attribute__((address_space(1))) void*)g,
      (__attribute__((address_space(3))) void*)l, 16, 0, 0);
}

// ---------------------------------------------------------------------------
// fp32 -> fp16 flat conversion, 4 elems/thread.
// ---------------------------------------------------------------------------
__global__ __launch_bounds__(256) void cvt_f16(const float* __restrict__ src,
                                               short* __restrict__ dst, int n) {
  int i = (blockIdx.x * 256 + threadIdx.x) << 2;
  if (i >= n) return;
  float4 v = *(const float4*)(src + i);
  short4 r;
  r.x = f2h(v.x); r.y = f2h(v.y); r.z = f2h(v.z); r.w = f2h(v.w);
  *(short4*)(dst + i) = r;
}

// ---------------------------------------------------------------------------
// C = act(A * B^T): A [M,Kd] f16 (short bits) lda, B [N,Kd] f16 ldb,
// output row stride ldc. mode: 0 = f32 out, 1 = f32 out + silu, 2 = f16 out.
// m97-verified structure: 128x128 tile, 256 thr = 4 waves, single LDS buffer,
// 2 barriers per 32-wide K-step, global_load_lds width 16, plain row-major
// LDS tile [row][32], 16x16x32 f16 MFMA, 4x4 tiles per wave.
// ---------------------------------------------------------------------------
__global__ __launch_bounds__(256) void gemm_f16(const short* __restrict__ A,
                                                const short* __restrict__ B,
                                                void* __restrict__ Cout,
                                                int ldc, int Kd, int lda, int ldb,
                                                int mode) {
  __shared__ __align__(16) short lds[8192];  // A tile 128x32 | B tile 128x32
  const int tid = threadIdx.x;
  const int lane = tid & 63;
  const int w = tid >> 6;
  const int m0 = blockIdx.x * 128;
  const int n0 = blockIdx.y * 128;

  // staging: lane -> row w*32 + lane/4 (and +16), granule (lane&3)*8 elems
  const int sr = w * 32 + (lane >> 2);
  const int sc = (lane & 3) << 3;
  const short* ga1 = A + (size_t)(m0 + sr) * lda + sc;
  const short* ga2 = ga1 + (size_t)16 * lda;
  const short* gb1 = B + (size_t)(n0 + sr) * ldb + sc;
  const short* gb2 = gb1 + (size_t)16 * ldb;
  short* la1 = &lds[(size_t)w * 1024];
  short* la2 = la1 + 512;
  short* lb1 = &lds[4096 + (size_t)w * 1024];
  short* lb2 = lb1 + 512;

  // fragment mapping (m89/m91-verified): A[m=lane&15][k=(lane>>4)*8+j]
  const int fr = lane & 15;
  const int kg = lane >> 4;
  const int wmB = (w & 1) * 64;
  const int wnB = (w >> 1) * 64;
  int aoff[4], boff[4];
#pragma unroll
  for (int i = 0; i < 4; ++i) {
    aoff[i] = (wmB + i * 16 + fr) * 32 + kg * 8;
    boff[i] = 4096 + (wnB + i * 16 + fr) * 32 + kg * 8;
  }

  f32x4 acc[4][4];
#pragma unroll
  for (int i = 0; i < 4; ++i)
#pragma unroll
    for (int j = 0; j < 4; ++j) acc[i][j] = (f32x4){0.f, 0.f, 0.f, 0.f};

  const int nk = Kd >> 5;
  for (int kt = 0; kt < nk; ++kt) {
    const int ko = kt << 5;
    __syncthreads();  // all waves done reading lds from previous iter
    gload_lds16(ga1 + ko, la1);
    gload_lds16(ga2 + ko, la2);
    gload_lds16(gb1 + ko, lb1);
    gload_lds16(gb2 + ko, lb2);
    __syncthreads();  // compiler drains vmcnt(0) before barrier -> tile ready
    f16x8 af[4], bf[4];
#pragma unroll
    for (int i = 0; i < 4; ++i) af[i] = *(const f16x8*)(lds + aoff[i]);
#pragma unroll
    for (int j = 0; j < 4; ++j) bf[j] = *(const f16x8*)(lds + boff[j]);
#pragma unroll
    for (int i = 0; i < 4; ++i)
#pragma unroll
      for (int j = 0; j < 4; ++j)
        acc[i][j] = __builtin_amdgcn_mfma_f32_16x16x32_f16(af[i], bf[j], acc[i][j], 0, 0, 0);
  }

  // epilogue: C/D layout col=lane&15, row=(lane>>4)*4+reg (m89/m91-verified)
#pragma unroll
  for (int i = 0; i < 4; ++i) {
    const int row = m0 + wmB + i * 16 + kg * 4;
#pragma unroll
    for (int j = 0; j < 4; ++j) {
      const int col = n0 + wnB + j * 16 + fr;
#pragma unroll
      for (int e = 0; e < 4; ++e) {
        float v = acc[i][j][e];
        if (mode == 1) v = v / (1.f + expf(-v));  // silu
        if (mode == 2) {
          ((_Float16*)Cout)[(size_t)(row + e) * ldc + col] = (_Float16)v;
        } else {
          ((float*)Cout)[(size_t)(row + e) * ldc + col] = v;
        }
      }
    }
  }
}

// ---------------------------------------------------------------------------
// Small projections (fp32): y = x @ [Wb;Wa]^T per row (18 outs) ->
// beta = 2*sigmoid, gexp = exp(-exp(A_log)*softplus(y+dt_bias)).
// ---------------------------------------------------------------------------
__global__ __launch_bounds__(256) void small_proj(const float* __restrict__ x,
                                                  const float* __restrict__ Wb,
                                                  const float* __restrict__ Wa,
                                                  const float* __restrict__ A_log,
                                                  const float* __restrict__ dt_bias,
                                                  float* __restrict__ beta_out,
                                                  float* __restrict__ gexp_out) {
  const int m = blockIdx.x;
  const int tid = threadIdx.x;
  const int lane = tid & 63;
  const int wv = tid >> 6;
  __shared__ float xs[DD];
  __shared__ float ybuf[18];
#pragma unroll
  for (int i = 0; i < DD / 256; ++i) xs[tid + 256 * i] = x[(size_t)m * DD + tid + 256 * i];
  __syncthreads();
  for (int n = wv; n < 18; n += 4) {
    const float* wrow = (n < 12) ? (Wb + (size_t)n * DD) : (Wa + (size_t)(n - 12) * DD);
    float p = 0.f;
#pragma unroll
    for (int i = 0; i < DD / 64; ++i) p = fmaf(xs[lane + 64 * i], wrow[lane + 64 * i], p);
#pragma unroll
    for (int off = 32; off; off >>= 1) p += __shfl_xor(p, off);
    if (lane == 0) ybuf[n] = p;
  }
  __syncthreads();
  if (tid < 12) {
    beta_out[(size_t)m * 12 + tid] = 2.f * sigmoidf_(ybuf[tid]);
  } else if (tid < 18) {
    int hh = tid - 12;
    float z = ybuf[tid] + dt_bias[hh];
    float sp = fmaxf(z, 0.f) + log1pf(expf(-fabsf(z)));
    float g = -expf(A_log[hh]) * sp;
    gexp_out[(size_t)m * HH + hh] = expf(g);
  }
}

// ---------------------------------------------------------------------------
// Sequential delta-rule recurrence (fp32) — structure identical to the
// round-1 version that passed; only input addressing changed (qkv buffer,
// row stride QKV_ST).
// ---------------------------------------------------------------------------
__global__ __launch_bounds__(256) void recurrence(const float* __restrict__ QKV,
                                                  const float* __restrict__ beta,
                                                  const float* __restrict__ gexp,
                                                  float* __restrict__ o) {
  constexpr int CH = VV / 16;  // 32 v-chunks
  const int bid = blockIdx.x;
  const int b = bid / (HH * CH);
  const int rem = bid % (HH * CH);
  const int hh = rem / CH;
  const int v0 = (rem % CH) * 16;
  const int tid = threadIdx.x;
  const int vl = tid >> 4;
  const int kq = tid & 15;
  const int lane = tid & 63;
  const int wv = tid >> 6;
  const int pidx = tid + 4 * (tid >> 4);

  __shared__ __align__(16) float ks[2][2][320];
  __shared__ __align__(16) float qs[2][320];
  __shared__ float vs[2][2][16];
  __shared__ float bs[2][2];
  __shared__ float gs[2];
  __shared__ float nr[2][2][4];

  float hreg[16];
#pragma unroll
  for (int i = 0; i < 16; ++i) hreg[i] = 0.f;

  const float scale = 0.0625f;  // 256^-0.5

  {
    const int m = b * TT;
    const float* prow = QKV + (size_t)m * QKV_ST;
    float rq = prow[QOFF + hh * KK + tid] * scale;
    float rk0 = prow[KOFF + 0 * KEY_DIM + hh * KK + tid];
    float rk1 = prow[KOFF + 1 * KEY_DIM + hh * KK + tid];
    float s0 = rk0 * rk0, s1 = rk1 * rk1;
#pragma unroll
    for (int off = 32; off; off >>= 1) { s0 += __shfl_xor(s0, off); s1 += __shfl_xor(s1, off); }
    if (lane == 0) { nr[0][0][wv] = s0; nr[0][1][wv] = s1; }
    ks[0][0][pidx] = rk0; ks[0][1][pidx] = rk1; qs[0][pidx] = rq;
    if (tid < 32) vs[0][tid >> 4][tid & 15] =
        prow[VOFF + (tid >> 4) * VAL_DIM + hh * VV + v0 + (tid & 15)];
    if (tid >= 32 && tid < 34) bs[0][tid - 32] = beta[(size_t)(m * NHOUSE + (tid - 32)) * HH + hh];
    if (tid == 34) gs[0] = gexp[(size_t)m * HH + hh];
  }
  __syncthreads();

  for (int t = 0; t < TT; ++t) {
    const int buf = t & 1;
    const int nb = buf ^ 1;
    const int tnx = (t + 1 < TT) ? (t + 1) : t;
    const int mn = b * TT + tnx;
    const float* prow = QKV + (size_t)mn * QKV_ST;

    float rq = prow[QOFF + hh * KK + tid] * scale;
    float rk0 = prow[KOFF + 0 * KEY_DIM + hh * KK + tid];
    float rk1 = prow[KOFF + 1 * KEY_DIM + hh * KK + tid];
    float rv = 0.f, rb = 0.f, rg = 0.f;
    if (tid < 32) rv = prow[VOFF + (tid >> 4) * VAL_DIM + hh * VV + v0 + (tid & 15)];
    if (tid >= 32 && tid < 34) rb = beta[(size_t)(mn * NHOUSE + (tid - 32)) * HH + hh];
    if (tid == 34) rg = gexp[(size_t)mn * HH + hh];

    float n0 = nr[buf][0][0] + nr[buf][0][1] + nr[buf][0][2] + nr[buf][0][3];
    float n1 = nr[buf][1][0] + nr[buf][1][1] + nr[buf][1][2] + nr[buf][1][3];
    float invj[2];
    invj[0] = rsqrt_nr(fmaxf(n0, 1e-24f));
    invj[1] = rsqrt_nr(fmaxf(n1, 1e-24f));
    const float ge = gs[buf];
    float bj[2];
    bj[0] = bs[buf][0] * invj[0];
    bj[1] = bs[buf][1] * invj[1];

#pragma unroll
    for (int i = 0; i < 16; ++i) hreg[i] *= ge;

#pragma unroll
    for (int j = 0; j < 2; ++j) {
      const float4* kb = (const float4*)&ks[buf][j][kq * 20];
      float4 x0 = kb[0], x1 = kb[1], x2 = kb[2], x3 = kb[3];
      float rk[16] = {x0.x, x0.y, x0.z, x0.w, x1.x, x1.y, x1.z, x1.w,
                      x2.x, x2.y, x2.z, x2.w, x3.x, x3.y, x3.z, x3.w};
      float p = 0.f;
#pragma unroll
      for (int i = 0; i < 16; ++i) p = fmaf(hreg[i], rk[i], p);
      p += __shfl_xor(p, 1); p += __shfl_xor(p, 2);
      p += __shfl_xor(p, 4); p += __shfl_xor(p, 8);
      p *= invj[j];
      const float wgt = bj[j] * (vs[buf][j][vl] - p);
#pragma unroll
      for (int i = 0; i < 16; ++i) hreg[i] = fmaf(wgt, rk[i], hreg[i]);
    }

    {
      const float4* qb = (const float4*)&qs[buf][kq * 20];
      float4 x0 = qb[0], x1 = qb[1], x2 = qb[2], x3 = qb[3];
      float qv[16] = {x0.x, x0.y, x0.z, x0.w, x1.x, x1.y, x1.z, x1.w,
                      x2.x, x2.y, x2.z, x2.w, x3.x, x3.y, x3.z, x3.w};
      float p = 0.f;
#pragma unroll
      for (int i = 0; i < 16; ++i) p = fmaf(hreg[i], qv[i], p);
      p += __shfl_xor(p, 1); p += __shfl_xor(p, 2);
      p += __shfl_xor(p, 4); p += __shfl_xor(p, 8);
      if (kq == 0) o[(size_t)((b * TT + t) * HH + hh) * VV + v0 + vl] = p;
    }

    float s0 = rk0 * rk0, s1 = rk1 * rk1;
#pragma unroll
    for (int off = 32; off; off >>= 1) { s0 += __shfl_xor(s0, off); s1 += __shfl_xor(s1, off); }
    if (lane == 0) { nr[nb][0][wv] = s0; nr[nb][1][wv] = s1; }
    ks[nb][0][pidx] = rk0; ks[nb][1][pidx] = rk1; qs[nb][pidx] = rq;
    if (tid < 32) vs[nb][tid >> 4][tid & 15] = rv;
    if (tid >= 32 && tid < 34) bs[nb][tid - 32] = rb;
    if (tid == 34) gs[nb] = rg;
    __syncthreads();
  }
}

// ---------------------------------------------------------------------------
// Gated RMSNorm. Reads o_mid fp32 + gate f16; writes o2 f16 (row stride 3072:
// head hh at cols [hh*512, hh*512+512)). grid = MM*HH, 256 threads.
// ---------------------------------------------------------------------------
__global__ __launch_bounds__(256) void rms_gate_kernel(const float* __restrict__ o,
                                                       const short* __restrict__ gate16,
                                                       const float* __restrict__ wn,
                                                       short* __restrict__ o2) {
  const int row = blockIdx.x;            // m*H + h
  const int m = row / HH;
  const int hh = row - m * HH;
  const int tid = threadIdx.x;
  const float* op = o + (size_t)row * VV;
  const _Float16* gp = (const _Float16*)gate16 + (size_t)m * VAL_DIM + hh * VV;
  float a0 = op[tid], a1 = op[tid + 256];
  float ss = a0 * a0 + a1 * a1;
#pragma unroll
  for (int off = 32; off; off >>= 1) ss += __shfl_xor(ss, off);
  __shared__ float red[4];
  const int lane = tid & 63, wv = tid >> 6;
  if (lane == 0) red[wv] = ss;
  __syncthreads();
  float tot = red[0] + red[1] + red[2] + red[3];
  float inv = rsqrt_nr(tot * (1.f / (float)VV) + 1e-5f);
  float r0 = a0 * inv * wn[tid] * sigmoidf_((float)gp[tid]);
  float r1 = a1 * inv * wn[tid + 256] * sigmoidf_((float)gp[tid + 256]);
  _Float16* dst = (_Float16*)o2 + (size_t)m * VAL_DIM + hh * VV;
  dst[tid] = (_Float16)r0;
  dst[tid + 256] = (_Float16)r1;
}

// ---------------------------------------------------------------------------
extern "C" void kernel_launch(void* const* d_in, const int* in_sizes, int n_in,
                              void* d_out, int out_size, void* d_ws, size_t ws_size,
                              hipStream_t stream) {
  (void)in_sizes; (void)n_in; (void)out_size; (void)ws_size;
  const float* x       = (const float*)d_in[0];
  const float* Wq      = (const float*)d_in[1];
  const float* Wk      = (const float*)d_in[2];
  const float* Wv      = (const float*)d_in[3];
  const float* Wb      = (const float*)d_in[4];
  const float* Wa      = (const float*)d_in[5];
  const float* A_log   = (const float*)d_in[6];
  const float* dt_bias = (const float*)d_in[7];
  const float* Wg      = (const float*)d_in[8];
  const float* Wo      = (const float*)d_in[9];
  const float* onw     = (const float*)d_in[10];
  float* out = (float*)d_out;
  float* ws = (float*)d_ws;

  float* qkv    = ws + OFF_QKV;
  short* gate16 = (short*)(ws + OFF_GATE);
  float* beta_w = ws + OFF_BETA;
  float* gexp_w = ws + OFF_GEXP;
  short* x16    = (short*)(ws + OFF_X16);
  short* wf16   = (short*)(ws + OFF_W16);
  float* o_mid  = ws + OFF_OMID;          // overlays x16+wf16 after GEMMs
  short* o2     = (short*)(ws + OFF_O2);  // overlays dead qkv after recurrence
  short* wo16   = (short*)(ws + OFF_WO16);

  // 1. conversions + small projections
  cvt_f16<<<4096, 256, 0, stream>>>(x, x16, MM * DD);
  small_proj<<<MM, 256, 0, stream>>>(x, Wb, Wa, A_log, dt_bias, beta_w, gexp_w);

  // 2. projection GEMMs (f16 inputs, fp32 out), sequential weight chunks.
  //    q: N=1536 cols [0,1536) silu
  cvt_f16<<<3072, 256, 0, stream>>>(Wq, wf16, KEY_DIM * DD);
  gemm_f16<<<dim3(MM / 128, KEY_DIM / 128), 256, 0, stream>>>(
      x16, wf16, qkv + QOFF, QKV_ST, DD, DD, DD, 1);
  //    k: N=3072 cols [1536,4608) silu
  cvt_f16<<<6144, 256, 0, stream>>>(Wk, wf16, KEY_DIM * NHOUSE * DD);
  gemm_f16<<<dim3(MM / 128, (KEY_DIM * NHOUSE) / 128), 256, 0, stream>>>(
      x16, wf16, qkv + KOFF, QKV_ST, DD, DD, DD, 1);
  //    v halves: N=3072 each, cols [4608,7680) and [7680,10752) silu
  cvt_f16<<<6144, 256, 0, stream>>>(Wv, wf16, VAL_DIM * DD);
  gemm_f16<<<dim3(MM / 128, VAL_DIM / 128), 256, 0, stream>>>(
      x16, wf16, qkv + VOFF, QKV_ST, DD, DD, DD, 1);
  cvt_f16<<<6144, 256, 0, stream>>>(Wv + (size_t)VAL_DIM * DD, wf16, VAL_DIM * DD);
  gemm_f16<<<dim3(MM / 128, VAL_DIM / 128), 256, 0, stream>>>(
      x16, wf16, qkv + VOFF + VAL_DIM, QKV_ST, DD, DD, DD, 1);
  //    gate: N=3072, f16 out, no act
  cvt_f16<<<6144, 256, 0, stream>>>(Wg, wf16, VAL_DIM * DD);
  gemm_f16<<<dim3(MM / 128, VAL_DIM / 128), 256, 0, stream>>>(
      x16, wf16, gate16, VAL_DIM, DD, DD, DD, 2);

  // 3. sequential recurrence (fp32)
  recurrence<<<BB * HH * (VV / 16), 256, 0, stream>>>(qkv, beta_w, gexp_w, o_mid);

  // 4. gated RMSNorm -> o2 f16 ; Wo -> f16
  rms_gate_kernel<<<MM * HH, 256, 0, stream>>>(o_mid, gate16, onw, o2);
  cvt_f16<<<6144, 256, 0, stream>>>(Wo, wo16, DD * VAL_DIM);

  // 5. output GEMM (f16 in, f32 out to d_out)
  gemm_f16<<<dim3(MM / 128, DD / 128), 256, 0, stream>>>(
      o2, wo16, out, DD, VAL_DIM, VAL_DIM, VAL_DIM, 0);
}